// Round 1
// baseline (12347.195 us; speedup 1.0000x reference)
//
#include <hip/hip_runtime.h>
#include <cstdint>
#include <cstddef>

// ---- problem constants ----
#define S_ 256
#define B_ 8
#define V_ 32000
#define D_ 512
#define N_ 16
#define R_ 512
#define G4_ 2048   // 4*R
#define SV_ 8192000 // S_*V_
#define CHUNK_ 64

typedef __attribute__((ext_vector_type(8))) short short8;
typedef __attribute__((ext_vector_type(4))) float f32x4;
typedef __attribute__((ext_vector_type(4))) unsigned short u16x4;
typedef __attribute__((ext_vector_type(4))) unsigned int u32x4;

__device__ __forceinline__ unsigned short f2b(float f){
  union { float f; unsigned int u; } v; v.f = f;
  unsigned int r = (v.u + 0x7fffu + ((v.u >> 16) & 1u)) >> 16;
  return (unsigned short)r;
}
__device__ __forceinline__ float b2f(unsigned short h){
  union { unsigned int u; float f; } v; v.u = ((unsigned int)h) << 16;
  return v.f;
}

// ---- permute+cast W_ih/W_hh rows: g = q*512+r  ->  g' = r*4+q (interleave gates) ----
__global__ void k_permute_cast(const float* __restrict__ src, unsigned short* __restrict__ dst,
                               const float* __restrict__ b1, const float* __restrict__ b2,
                               float* __restrict__ bias_out)
{
  int bid = blockIdx.x;              // n*2048+g
  int n = bid >> 11, g = bid & 2047;
  int q = g >> 9, r = g & 511;
  int gp = (r << 2) | q;
  const float* s = src + (size_t)bid * 512;
  unsigned short* d = dst + ((size_t)(n * 2048 + gp)) * 512;
  int l = threadIdx.x; // 64
  f32x4 a = ((const f32x4*)s)[l*2];
  f32x4 c = ((const f32x4*)s)[l*2+1];
  u16x4 o1, o2;
  o1[0]=f2b(a[0]); o1[1]=f2b(a[1]); o1[2]=f2b(a[2]); o1[3]=f2b(a[3]);
  o2[0]=f2b(c[0]); o2[1]=f2b(c[1]); o2[2]=f2b(c[2]); o2[3]=f2b(c[3]);
  ((u16x4*)d)[l*2] = o1; ((u16x4*)d)[l*2+1] = o2;
  if (l == 0 && bias_out) bias_out[n*2048 + gp] = b1[bid] + b2[bid];
}

// ---- plain fp32 -> bf16 cast, 8 elems/thread ----
__global__ void k_cast(const float* __restrict__ src, unsigned short* __restrict__ dst)
{
  int i = blockIdx.x * 256 + threadIdx.x;
  f32x4 a = ((const f32x4*)src)[i*2];
  f32x4 c = ((const f32x4*)src)[i*2+1];
  u16x4 o1, o2;
  o1[0]=f2b(a[0]); o1[1]=f2b(a[1]); o1[2]=f2b(a[2]); o1[3]=f2b(a[3]);
  o2[0]=f2b(c[0]); o2[1]=f2b(c[1]); o2[2]=f2b(c[2]); o2[3]=f2b(c[3]);
  ((u16x4*)dst)[i*2] = o1; ((u16x4*)dst)[i*2+1] = o2;
}

// ---- transpose W_np [n][d][r] -> WnpT [n][r][d] (bf16 out) ----
__global__ void k_transpose_np(const float* __restrict__ src, unsigned short* __restrict__ dst)
{
  __shared__ float tile[64][65];
  int bid = blockIdx.x;                 // n*64 + dt*8 + rt
  int n = bid >> 6, dt = (bid >> 3) & 7, rt = bid & 7;
  int tid = threadIdx.x;
  int row = tid >> 2, c4 = (tid & 3) * 16;
  const float* s = src + ((size_t)n*512 + dt*64 + row)*512 + rt*64 + c4;
#pragma unroll
  for (int i = 0; i < 16; i += 4){
    f32x4 v = *(const f32x4*)(s + i);
    tile[row][c4+i] = v[0]; tile[row][c4+i+1] = v[1];
    tile[row][c4+i+2] = v[2]; tile[row][c4+i+3] = v[3];
  }
  __syncthreads();
  unsigned short* d = dst + ((size_t)n*512 + rt*64 + row)*512 + dt*64 + c4;
#pragma unroll
  for (int i = 0; i < 16; i += 4){
    u16x4 o;
    o[0]=f2b(tile[c4+i][row]);   o[1]=f2b(tile[c4+i+1][row]);
    o[2]=f2b(tile[c4+i+2][row]); o[3]=f2b(tile[c4+i+3][row]);
    *(u16x4*)(d + i) = o;
  }
}

// ---- transpose op_w [d][e] -> op_wT [e][d] fp32 ----
__global__ void k_transpose_op(const float* __restrict__ src, float* __restrict__ dst)
{
  __shared__ float tile[64][65];
  int bid = blockIdx.x; int dt = bid >> 3, et = bid & 7;
  int tid = threadIdx.x;
  int row = tid >> 2, c4 = (tid & 3) * 16;
  const float* s = src + ((size_t)(dt*64 + row))*512 + et*64 + c4;
#pragma unroll
  for (int i = 0; i < 16; i += 4){
    f32x4 v = *(const f32x4*)(s + i);
    tile[row][c4+i] = v[0]; tile[row][c4+i+1] = v[1];
    tile[row][c4+i+2] = v[2]; tile[row][c4+i+3] = v[3];
  }
  __syncthreads();
  float* d = dst + ((size_t)(et*64 + row))*512 + dt*64 + c4;
#pragma unroll
  for (int i = 0; i < 16; i++) d[i] = tile[c4+i][row];
}

// ---- embedding gather: xs[t*8+b][d] fp32 + bf16 copy ----
__global__ void k_embed(const int* __restrict__ x, const float* __restrict__ emb,
                        float* __restrict__ xs, unsigned short* __restrict__ xs_bf)
{
  int row = blockIdx.x;       // t*8+b
  int t = row >> 3, b = row & 7;
  int tok = x[b*S_ + t];
  const f32x4* e = (const f32x4*)(emb + (size_t)tok*512);
  int l = threadIdx.x; // 64
  f32x4 v0 = e[l*2], v1 = e[l*2+1];
  f32x4* xo = (f32x4*)(xs + (size_t)row*512);
  xo[l*2] = v0; xo[l*2+1] = v1;
  u16x4 o0, o1;
  o0[0]=f2b(v0[0]); o0[1]=f2b(v0[1]); o0[2]=f2b(v0[2]); o0[3]=f2b(v0[3]);
  o1[0]=f2b(v1[0]); o1[1]=f2b(v1[1]); o1[2]=f2b(v1[2]); o1[3]=f2b(v1[3]);
  u16x4* xb = (u16x4*)(xs_bf + (size_t)row*512);
  xb[l*2] = o0; xb[l*2+1] = o1;
}

// ---- init c_state f32, h buffer0 bf16, zero barrier flags ----
__global__ void k_init(const float* __restrict__ h0, const float* __restrict__ c0,
                       float* __restrict__ c_state, unsigned short* __restrict__ h_buf0,
                       unsigned int* __restrict__ flags)
{
  int i = blockIdx.x * 256 + threadIdx.x;   // grid 256 -> 65536 = [16][8][512]
  c_state[i] = c0[i];
  h_buf0[i] = f2b(h0[i]);
  if (blockIdx.x == 0) flags[threadIdx.x] = 0;
}

// ---- generic 128x128-tile bf16 MFMA GEMM: C[m][col] = sum_k A[m][k]*B[col][k] + bias[col]
// MODE 0: gates chunk -> bf16 [t][n][g'][b] ; MODE 1: fp32 row-major (strideC/y) ;
// MODE 2: head -> fp32 d_out [b][t][v] ; MODE 3: bf16 row-major
template<int MODE>
__global__ __launch_bounds__(256)
void k_gemm(const unsigned short* __restrict__ A, const unsigned short* __restrict__ Bm,
            const float* __restrict__ bias, void* __restrict__ Cout,
            int M, int Ncol, int ldc, int nblocks,
            long strideA, long strideB, long strideC, long strideBias)
{
  __shared__ unsigned short lA[128*56];
  __shared__ unsigned short lB[128*56];
  const unsigned short* Ap = A + (size_t)blockIdx.y * strideA;
  const unsigned short* Bp = Bm + (size_t)blockIdx.y * strideB;
  const float* bp = bias ? bias + (size_t)blockIdx.y * strideBias : nullptr;
  int bid = blockIdx.x;
  int mb = bid / nblocks, nb = bid - mb*nblocks;
  int m0 = mb*128, n0 = nb*128;
  int tid = threadIdx.x;
  int wv = tid >> 6, lane = tid & 63;
  int quad = lane >> 4, l16 = lane & 15;
  int wm = wv & 1, wn = wv >> 1;
  f32x4 acc[4][4];
  f32x4 z = {0.f,0.f,0.f,0.f};
#pragma unroll
  for (int i=0;i<4;i++)
#pragma unroll
    for (int j=0;j<4;j++) acc[i][j] = z;

  int lrow = tid >> 2;
  int lkc  = (tid & 3) * 8;
  for (int k0 = 0; k0 < 512; k0 += 32){
    __syncthreads();
#pragma unroll
    for (int h = 0; h < 2; h++){
      int row = lrow + h*64;
      int ar = m0 + row; if (ar >= M) ar = M - 1;
      u32x4 va = *(const u32x4*)(Ap + (size_t)ar*512 + k0 + lkc);
      *(u32x4*)(lA + row*56 + lkc) = va;
      int br = n0 + row; if (br >= Ncol) br = Ncol - 1;
      u32x4 vb = *(const u32x4*)(Bp + (size_t)br*512 + k0 + lkc);
      *(u32x4*)(lB + row*56 + lkc) = vb;
    }
    __syncthreads();
    short8 af[4], bfr[4];
#pragma unroll
    for (int i=0;i<4;i++)
      af[i] = *(const short8*)(lA + (wm*64 + i*16 + l16)*56 + quad*8);
#pragma unroll
    for (int j=0;j<4;j++)
      bfr[j] = *(const short8*)(lB + (wn*64 + j*16 + l16)*56 + quad*8);
#pragma unroll
    for (int i=0;i<4;i++)
#pragma unroll
      for (int j=0;j<4;j++)
        acc[i][j] = __builtin_amdgcn_mfma_f32_16x16x32_bf16(af[i], bfr[j], acc[i][j], 0, 0, 0);
  }
  // epilogue
#pragma unroll
  for (int j = 0; j < 4; j++){
    int col = n0 + wn*64 + j*16 + l16;
    float bv = 0.0f;
    if (bp != nullptr && col < Ncol) bv = bp[col];
#pragma unroll
    for (int i = 0; i < 4; i++){
      int rbase = m0 + wm*64 + i*16 + quad*4;
      f32x4 v = acc[i][j];
      if (MODE == 0){
        int tt = rbase >> 3, b0 = rbase & 7;
        int nn = col >> 11, gp = col & 2047;
        u16x4 pk;
        pk[0]=f2b(v[0]+bv); pk[1]=f2b(v[1]+bv); pk[2]=f2b(v[2]+bv); pk[3]=f2b(v[3]+bv);
        *(u16x4*)((unsigned short*)Cout + (((size_t)tt*16 + nn)*2048 + (size_t)gp)*8 + b0) = pk;
      } else if (MODE == 1){
        float* O = (float*)Cout + (size_t)blockIdx.y * strideC;
#pragma unroll
        for (int r = 0; r < 4; r++){
          int m = rbase + r;
          if (m < M && col < Ncol) O[(size_t)m*ldc + col] = v[r] + bv;
        }
      } else if (MODE == 2){
        float* O = (float*)Cout;
#pragma unroll
        for (int r = 0; r < 4; r++){
          int m = rbase + r;
          int bb = m & 7, tt = m >> 3;
          O[(size_t)bb*SV_ + (size_t)tt*V_ + col] = v[r] + bv;
        }
      } else {
        unsigned short* O = (unsigned short*)Cout + (size_t)blockIdx.y * strideC;
#pragma unroll
        for (int r = 0; r < 4; r++){
          int m = rbase + r;
          if (m < M && col < Ncol) O[(size_t)m*ldc + col] = f2b(v[r] + bv);
        }
      }
    }
  }
}

// ---- persistent LSTM recurrence over one 64-step chunk ----
// grid 256 WGs (1/CU), 256 threads. WG (n, sl): gate-cols [sl*128, sl*128+128) of layer n
// == r in [sl*32, sl*32+32). W_hh slice held in REGISTERS (2 tiles x 16 k-frags / wave).
// c-state in registers for the whole chunk. h broadcast via global double buffer + flag barrier.
__global__ __launch_bounds__(256, 1)
void k_lstm_persist(const unsigned short* __restrict__ W_hhp,
                    const unsigned short* __restrict__ gates_buf,
                    unsigned short* __restrict__ h_all,
                    unsigned short* __restrict__ h_bufs,   // 2 x [16][8][512] bf16
                    float* __restrict__ h_state, float* __restrict__ c_state,
                    unsigned int* __restrict__ flags, int chunk)
{
  __shared__ __align__(16) unsigned char sh[16384];   // h tile [16 rows][1024 B], XOR-swizzled
  __shared__ float gsh[4][2][8][20];
  const int wg = blockIdx.x;
  const int n = wg >> 4, sl = wg & 15;
  const int tid = threadIdx.x;
  const int wv = tid >> 6, lane = tid & 63;
  const int quad = lane >> 4, l16 = lane & 15;
  const int gp0 = sl*128 + wv*32;          // this wave's first gate-col (2 tiles of 16)

  // weight fragments -> registers (128 VGPRs)
  short8 wfr[2][16];
#pragma unroll
  for (int ct = 0; ct < 2; ct++){
    const unsigned short* wp = W_hhp + ((size_t)(n*2048 + gp0 + ct*16 + l16))*512 + quad*8;
#pragma unroll
    for (int k = 0; k < 16; k++)
      wfr[ct][k] = *(const short8*)(wp + k*32);
  }

  const int pb = lane >> 2, prl = lane & 3;     // valid for lane<32
  const int rbase = sl*32 + wv*8;
  float creg[2] = {0.f, 0.f}, hlast[2] = {0.f, 0.f};
  if (lane < 32){
#pragma unroll
    for (int ct = 0; ct < 2; ct++)
      creg[ct] = c_state[((size_t)n*8 + pb)*512 + rbase + ct*4 + prl];
  }

  // zero pad rows 8..15 of the h tile (stay zero forever)
  { u32x4 z = {0,0,0,0};
    *(u32x4*)(sh + 8192 + tid*32) = z;
    *(u32x4*)(sh + 8192 + tid*32 + 16) = z; }

  const int sb = tid >> 5, skc = tid & 31;      // staging: row b, 16-elem chunk
  const int sswz = (sb & 7) << 4;
  const int aswz = (l16 & 7) << 4;

  for (int ls = 0; ls < CHUNK_; ls++){
    const int t = chunk*CHUNK_ + ls;
    // ---- stage h (8 rows x 512 bf16) global -> swizzled LDS ----
    { const unsigned short* hin = h_bufs + (size_t)(t & 1)*65536 + (size_t)n*4096
                                   + (size_t)sb*512 + skc*16;
      u32x4 v0 = *(const u32x4*)(hin);
      u32x4 v1 = *(const u32x4*)(hin + 8);
      *(u32x4*)(sh + sb*1024 + ((skc*32) ^ sswz)) = v0;
      *(u32x4*)(sh + sb*1024 + ((skc*32 + 16) ^ sswz)) = v1; }
    __syncthreads();

    // ---- gates_in + h @ W_hh (2 tiles / wave) ----
    f32x4 acc0, acc1;
    if (quad < 2){
      const unsigned short* gptr = gates_buf + ((size_t)(ls*16 + n)*2048 + gp0 + l16)*8 + quad*4;
      u16x4 g0 = *(const u16x4*)gptr;
      u16x4 g1 = *(const u16x4*)(gptr + 128);    // next 16-col tile
      acc0[0]=b2f(g0[0]); acc0[1]=b2f(g0[1]); acc0[2]=b2f(g0[2]); acc0[3]=b2f(g0[3]);
      acc1[0]=b2f(g1[0]); acc1[1]=b2f(g1[1]); acc1[2]=b2f(g1[2]); acc1[3]=b2f(g1[3]);
    } else {
      f32x4 z = {0.f,0.f,0.f,0.f};
      acc0 = z; acc1 = z;
    }
#pragma unroll
    for (int k = 0; k < 16; k++){
      short8 af = *(const short8*)(sh + l16*1024 + ((k*64 + quad*16) ^ aswz));
      acc0 = __builtin_amdgcn_mfma_f32_16x16x32_bf16(af, wfr[0][k], acc0, 0, 0, 0);
      acc1 = __builtin_amdgcn_mfma_f32_16x16x32_bf16(af, wfr[1][k], acc1, 0, 0, 0);
    }

    // ---- regroup gates per (b,r) via LDS, LSTM pointwise ----
    if (quad < 2){
#pragma unroll
      for (int r = 0; r < 4; r++){
        gsh[wv][0][quad*4+r][l16] = acc0[r];
        gsh[wv][1][quad*4+r][l16] = acc1[r];
      }
    }
    __syncthreads();
    if (lane < 32){
#pragma unroll
      for (int ct = 0; ct < 2; ct++){
        float gi = gsh[wv][ct][pb][prl*4+0];
        float gf = gsh[wv][ct][pb][prl*4+1];
        float gg = gsh[wv][ct][pb][prl*4+2];
        float go = gsh[wv][ct][pb][prl*4+3];
        float cv = creg[ct];
        float si = 1.f/(1.f + expf(-gi));
        float sf = 1.f/(1.f + expf(-gf));
        float so = 1.f/(1.f + expf(-go));
        float cn = sf*cv + si*tanhf(gg);
        float hn = so*tanhf(cn);
        creg[ct] = cn; hlast[ct] = hn;
        int r = rbase + ct*4 + prl;
        unsigned short hb = f2b(hn);
        h_bufs[(size_t)((t+1)&1)*65536 + ((size_t)n*8 + pb)*512 + r] = hb;
        h_all[((size_t)n*2048 + (size_t)t*8 + pb)*512 + r] = hb;
      }
    }

    // ---- device-wide barrier (flag array, monotonic targets) ----
    if (ls != CHUNK_-1){
      __threadfence();
      __syncthreads();
      if (tid == 0)
        __hip_atomic_store(flags + wg, (unsigned int)(t+1), __ATOMIC_RELEASE, __HIP_MEMORY_SCOPE_AGENT);
      if (wv == 0){
        const unsigned int tgt = (unsigned int)(t+1);
        int pend;
        do {
          unsigned int f0 = __hip_atomic_load(flags + lane,       __ATOMIC_RELAXED, __HIP_MEMORY_SCOPE_AGENT);
          unsigned int f1 = __hip_atomic_load(flags + lane + 64,  __ATOMIC_RELAXED, __HIP_MEMORY_SCOPE_AGENT);
          unsigned int f2 = __hip_atomic_load(flags + lane + 128, __ATOMIC_RELAXED, __HIP_MEMORY_SCOPE_AGENT);
          unsigned int f3 = __hip_atomic_load(flags + lane + 192, __ATOMIC_RELAXED, __HIP_MEMORY_SCOPE_AGENT);
          unsigned int mn  = f0 < f1 ? f0 : f1;
          unsigned int mn2 = f2 < f3 ? f2 : f3;
          mn = mn < mn2 ? mn : mn2;
          pend = !__all((int)(mn >= tgt));
          if (pend) __builtin_amdgcn_s_sleep(1);
        } while (pend);
      }
      __syncthreads();
      __threadfence();
    }
  }
  // persist recurrent state (c for next chunk; h f32 for final output)
  if (lane < 32){
#pragma unroll
    for (int ct = 0; ct < 2; ct++){
      int r = rbase + ct*4 + prl;
      c_state[((size_t)n*8 + pb)*512 + r] = creg[ct];
      h_state[((size_t)n*8 + pb)*512 + r] = hlast[ct];
    }
  }
}

// ---- batched attention for one 64-step chunk: scores+softmax+att, f32 ----
__global__ __launch_bounds__(256)
void k_att2(const float* __restrict__ kv, const float* __restrict__ q_all,
            float* __restrict__ att_all, int c)
{
  __shared__ float sV[16][528];
  __shared__ float sQ[512];
  __shared__ float sS[8][16];
  __shared__ float sW[8][16];
  int row = blockIdx.x, tid = threadIdx.x;   // row in [0,512)
  int grow = c*512 + row;                    // global t*8+b
  for (int idx = tid; idx < 2048; idx += 256){
    int nn = idx >> 7, e4 = (idx & 127) * 4;
    f32x4 v = *(const f32x4*)(kv + ((size_t)nn*512 + row)*1024 + 512 + e4);
    *(f32x4*)&sV[nn][e4] = v;
  }
  if (tid < 128){
    f32x4 q4 = *(const f32x4*)(q_all + (size_t)grow*512 + tid*4);
    *(f32x4*)&sQ[tid*4] = q4;
  }
  __syncthreads();
  if (tid < 128){
    int h = tid >> 4, nn = tid & 15;
    const f32x4* kp = (const f32x4*)(kv + ((size_t)nn*512 + row)*1024 + h*64);
    const f32x4* qp = (const f32x4*)(sQ + h*64);
    float s = 0.f;
#pragma unroll
    for (int i = 0; i < 16; i++){
      f32x4 k4 = kp[i], q4 = qp[i];
      s += k4[0]*q4[0] + k4[1]*q4[1] + k4[2]*q4[2] + k4[3]*q4[3];
    }
    sS[h][nn] = s * 0.125f;
  }
  __syncthreads();
  if (tid < 8){
    float mx = -1e30f;
#pragma unroll
    for (int nn = 0; nn < 16; nn++) mx = fmaxf(mx, sS[tid][nn]);
    float ex[16]; float sum = 0.f;
#pragma unroll
    for (int nn = 0; nn < 16; nn++){ ex[nn] = expf(sS[tid][nn] - mx); sum += ex[nn]; }
    float inv = 1.f/sum;
#pragma unroll
    for (int nn = 0; nn < 16; nn++) sW[tid][nn] = ex[nn]*inv;
  }
  __syncthreads();
  for (int d = tid; d < 512; d += 256){
    int h = d >> 6;
    float a = 0.f;
#pragma unroll
    for (int nn = 0; nn < 16; nn++) a += sW[h][nn] * sV[nn][d];
    att_all[(size_t)grow*512 + d] = a;
  }
}

// ---- f32 tiled op-projection + bias + residual: y = att @ op_wT + op_b + xs ----
__global__ __launch_bounds__(256)
void k_opproj(const float* __restrict__ att, const float* __restrict__ opT,
              const float* __restrict__ op_b, const float* __restrict__ xs,
              float* __restrict__ y)
{
  __shared__ float sA[64][36];
  __shared__ float sB[32][68];
  int mb = blockIdx.x >> 3, nb = blockIdx.x & 7;   // 32 x 8
  int m0 = mb*64, n0 = nb*64;
  int tid = threadIdx.x;
  int ty = tid >> 4, tx = tid & 15;
  float acc[4][4] = {};
  int ra = tid >> 2, ka = (tid & 3) * 8;
  int rb = tid >> 3, cbq = (tid & 7) * 8;
  for (int k0 = 0; k0 < 512; k0 += 32){
    __syncthreads();
    f32x4 a0 = *(const f32x4*)(att + (size_t)(m0+ra)*512 + k0 + ka);
    f32x4 a1 = *(const f32x4*)(att + (size_t)(m0+ra)*512 + k0 + ka + 4);
    f32x4 b0 = *(const f32x4*)(opT + (size_t)(k0+rb)*512 + n0 + cbq);
    f32x4 b1 = *(const f32x4*)(opT + (size_t)(k0+rb)*512 + n0 + cbq + 4);
    *(f32x4*)&sA[ra][ka] = a0;   *(f32x4*)&sA[ra][ka+4] = a1;
    *(f32x4*)&sB[rb][cbq] = b0;  *(f32x4*)&sB[rb][cbq+4] = b1;
    __syncthreads();
#pragma unroll
    for (int kk = 0; kk < 32; kk++){
      float av[4], bv[4];
#pragma unroll
      for (int i=0;i<4;i++) av[i] = sA[ty*4+i][kk];
#pragma unroll
      for (int j=0;j<4;j++) bv[j] = sB[kk][tx*4+j];
#pragma unroll
      for (int i=0;i<4;i++)
#pragma unroll
        for (int j=0;j<4;j++) acc[i][j] += av[i]*bv[j];
    }
  }
  f32x4 ob = *(const f32x4*)(op_b + n0 + tx*4);
#pragma unroll
  for (int i=0;i<4;i++){
    int m = m0 + ty*4 + i;
    f32x4 xr = *(const f32x4*)(xs + (size_t)m*512 + n0 + tx*4);
    f32x4 o;
#pragma unroll
    for (int j=0;j<4;j++) o[j] = acc[i][j] + ob[j] + xr[j];
    *(f32x4*)(y + (size_t)m*512 + n0 + tx*4) = o;
  }
}

// ---- layernorm rows -> bf16 mixed ----
__global__ void k_ln(const float* __restrict__ y, const float* __restrict__ ln_g,
                     const float* __restrict__ ln_b, unsigned short* __restrict__ mixed)
{
  int row = blockIdx.x, lane = threadIdx.x;  // 64 threads
  const float* yr = y + (size_t)row*512 + lane*8;
  f32x4 v0 = *(const f32x4*)yr;
  f32x4 v1 = *(const f32x4*)(yr + 4);
  float s = v0[0]+v0[1]+v0[2]+v0[3]+v1[0]+v1[1]+v1[2]+v1[3];
#pragma unroll
  for (int off = 32; off; off >>= 1) s += __shfl_xor(s, off);
  float mu = s * (1.f/512.f);
  float d[8];
#pragma unroll
  for (int i=0;i<4;i++){ d[i] = v0[i]-mu; d[4+i] = v1[i]-mu; }
  float p = 0.f;
#pragma unroll
  for (int i=0;i<8;i++) p += d[i]*d[i];
#pragma unroll
  for (int off = 32; off; off >>= 1) p += __shfl_xor(p, off);
  float rstd = rsqrtf(p*(1.f/512.f) + 1e-5f);
  f32x4 g0 = *(const f32x4*)(ln_g + lane*8);
  f32x4 g1 = *(const f32x4*)(ln_g + lane*8 + 4);
  f32x4 b0 = *(const f32x4*)(ln_b + lane*8);
  f32x4 b1 = *(const f32x4*)(ln_b + lane*8 + 4);
  u16x4 o0, o1;
#pragma unroll
  for (int i=0;i<4;i++){
    o0[i] = f2b(d[i]*rstd*g0[i] + b0[i]);
    o1[i] = f2b(d[4+i]*rstd*g1[i] + b1[i]);
  }
  unsigned short* mr = mixed + (size_t)row*512 + lane*8;
  *(u16x4*)mr = o0; *(u16x4*)(mr + 4) = o1;
}

extern "C" void kernel_launch(void* const* d_in, const int* in_sizes, int n_in,
                              void* d_out, int out_size, void* d_ws, size_t ws_size,
                              hipStream_t stream)
{
  const int*   x      = (const int*)  d_in[0];
  const float* h0     = (const float*)d_in[1];
  const float* c0     = (const float*)d_in[2];
  const float* emb    = (const float*)d_in[3];
  const float* W_ih   = (const float*)d_in[4];
  const float* b_ih   = (const float*)d_in[5];
  const float* W_hh   = (const float*)d_in[6];
  const float* b_hh   = (const float*)d_in[7];
  const float* W_np   = (const float*)d_in[8];
  const float* b_np   = (const float*)d_in[9];
  const float* in_w   = (const float*)d_in[10];
  const float* in_b   = (const float*)d_in[11];
  const float* op_w   = (const float*)d_in[12];
  const float* op_b   = (const float*)d_in[13];
  const float* ln_g   = (const float*)d_in[14];
  const float* ln_b   = (const float*)d_in[15];
  const float* head_w = (const float*)d_in[16];
  const float* head_b = (const float*)d_in[17];
  float* out = (float*)d_out;

  char* p = (char*)d_ws;
  unsigned short* gates_buf = (unsigned short*)p;         p += 33554432; // [64][16][2048][8] bf16; later kv_chunk f32
  unsigned short* WnpT      = (unsigned short*)gates_buf;                // alias: pre-loop only
  unsigned short* W_ihp     = (unsigned short*)p;         p += 33554432; // later att_all+y_all f32
  unsigned short* W_hhp     = (unsigned short*)p;         p += 33554432;
  unsigned short* headw_bf  = (unsigned short*)p;         p += 32768000;
  unsigned short* A_kv      = (unsigned short*)p;         p += 16777216;
  unsigned short* h_all     = (unsigned short*)p;         p += 33554432; // [16][2048][512] bf16
  float*          xs        = (float*)p;                  p += 4194304;
  float*          q_all     = (float*)p;                  p += 4194304;
  unsigned short* mixed_bf  = (unsigned short*)p;         p += 2097152;
  unsigned short* xs_bf     = (unsigned short*)p;         p += 2097152;
  unsigned short* Wkv_bf    = (unsigned short*)p;         p += 1048576;
  unsigned short* Wq_bf     = (unsigned short*)p;         p += 524288;
  float*          op_wT     = (float*)p;                  p += 1048576;
  float*          h_state   = (float*)p;                  p += 262144;
  float*          c_state   = (float*)p;                  p += 262144;
  unsigned short* h_bufs    = (unsigned short*)p;         p += 262144;  // 2 x [16][8][512] bf16
  float*          bias_g    = (float*)p;                  p += 131072;
  float*          bias_kvw  = (float*)p;                  p += 65536;
  unsigned short* bnp_bf    = (unsigned short*)p;         p += 16384;
  unsigned int*   flags     = (unsigned int*)p;           p += 1024;

  // ---- precompute ----
  k_permute_cast<<<32768, 64, 0, stream>>>(W_ih, W_ihp, b_ih, b_hh, bias_g);
  k_permute_cast<<<32768, 64, 0, stream>>>(W_hh, W_hhp, nullptr, nullptr, nullptr);
  k_cast<<<8000, 256, 0, stream>>>(head_w, headw_bf);
  k_cast<<<256, 256, 0, stream>>>(in_w + 512*512, Wkv_bf);   // rows 512..1535 (Wk||Wv)
  k_cast<<<128, 256, 0, stream>>>(in_w, Wq_bf);              // rows 0..511
  k_cast<<<4, 256, 0, stream>>>(b_np, bnp_bf);
  k_transpose_np<<<1024, 256, 0, stream>>>(W_np, WnpT);
  k_transpose_op<<<64, 256, 0, stream>>>(op_w, op_wT);
  // A_kv[n][e'][r] = sum_d Wkv[e'][d] * W_np[n][d][r]
  k_gemm<3><<<dim3(32, 16), 256, 0, stream>>>(Wkv_bf, WnpT, nullptr, A_kv,
                                              1024, 512, 512, 4, 0L, 262144L, 524288L, 0L);
  // bias_kv[n][e'] = sum_d b_np[n][d]*Wkv[e'][d] + in_b[512+e']
  k_gemm<1><<<dim3(8, 1), 256, 0, stream>>>(bnp_bf, Wkv_bf, in_b + 512, bias_kvw,
                                            16, 1024, 1024, 8, 0L, 0L, 0L, 0L);
  k_embed<<<2048, 64, 0, stream>>>(x, emb, xs, xs_bf);
  // q_all = xs @ Wq^T + bq
  k_gemm<1><<<dim3(64, 1), 256, 0, stream>>>(xs_bf, Wq_bf, in_b, q_all,
                                             2048, 512, 512, 4, 0L, 0L, 0L, 0L);
  k_init<<<256, 256, 0, stream>>>(h0, c0, c_state, h_bufs, flags);

  // ---- recurrence: 4 chunks of 64 steps, persistent kernel per chunk ----
  for (int c = 0; c < 4; c++){
    k_gemm<0><<<dim3(1024, 1), 256, 0, stream>>>(xs_bf + (size_t)c*262144, W_ihp, bias_g,
                                                 gates_buf, 512, 32768, 0, 256, 0L, 0L, 0L, 0L);
    k_lstm_persist<<<256, 256, 0, stream>>>(W_hhp, gates_buf, h_all, h_bufs,
                                            h_state, c_state, flags, c);
  }

  // ---- batched kv + attention (gates_buf reused as f32 kv chunk [16][512][1024]) ----
  float* kv_chunk = (float*)gates_buf;
  float* att_all  = (float*)W_ihp;            // 2048x512 f32
  float* y_all    = att_all + 2048*512;       // 2048x512 f32
  for (int c = 0; c < 4; c++){
    k_gemm<1><<<dim3(32, 16), 256, 0, stream>>>(h_all + (size_t)c*262144, A_kv, bias_kvw,
                                                kv_chunk, 512, 1024, 1024, 8,
                                                1048576L, 524288L, 524288L, 1024L);
    k_att2<<<512, 256, 0, stream>>>(kv_chunk, q_all, att_all, c);
  }
  k_opproj<<<256, 256, 0, stream>>>(att_all, op_wT, op_b, xs, y_all);
  k_ln<<<2048, 64, 0, stream>>>(y_all, ln_g, ln_b, mixed_bf);

  // ---- head GEMM: logits[b][t][v] ----
  k_gemm<2><<<dim3(4000, 1), 256, 0, stream>>>(mixed_bf, headw_bf, head_b, out,
                                               2048, 32000, 0, 250, 0L, 0L, 0L, 0L);
  // ---- hf, cf ----
  hipMemcpyAsync(out + (size_t)B_*SV_,         h_state, 65536*sizeof(float),
                 hipMemcpyDeviceToDevice, stream);
  hipMemcpyAsync(out + (size_t)B_*SV_ + 65536, c_state, 65536*sizeof(float),
                 hipMemcpyDeviceToDevice, stream);
}

// Round 2
// 1813.645 us; speedup vs baseline: 6.8079x; 6.8079x over previous
//
#include <hip/hip_runtime.h>
#include <cstdint>
#include <cstddef>

// ---- problem constants ----
#define S_ 256
#define B_ 8
#define V_ 32000
#define D_ 512
#define N_ 16
#define R_ 512
#define G4_ 2048   // 4*R
#define SV_ 8192000 // S_*V_
#define CHUNK_ 64

typedef __attribute__((ext_vector_type(8))) short short8;
typedef __attribute__((ext_vector_type(4))) float f32x4;
typedef __attribute__((ext_vector_type(4))) unsigned short u16x4;
typedef __attribute__((ext_vector_type(4))) unsigned int u32x4;

__device__ __forceinline__ unsigned short f2b(float f){
  union { float f; unsigned int u; } v; v.f = f;
  unsigned int r = (v.u + 0x7fffu + ((v.u >> 16) & 1u)) >> 16;
  return (unsigned short)r;
}
__device__ __forceinline__ float b2f(unsigned short h){
  union { unsigned int u; float f; } v; v.u = ((unsigned int)h) << 16;
  return v.f;
}

// ---- permute+cast W_ih/W_hh rows: g = q*512+r  ->  g' = r*4+q (interleave gates) ----
__global__ void k_permute_cast(const float* __restrict__ src, unsigned short* __restrict__ dst,
                               const float* __restrict__ b1, const float* __restrict__ b2,
                               float* __restrict__ bias_out)
{
  int bid = blockIdx.x;              // n*2048+g
  int n = bid >> 11, g = bid & 2047;
  int q = g >> 9, r = g & 511;
  int gp = (r << 2) | q;
  const float* s = src + (size_t)bid * 512;
  unsigned short* d = dst + ((size_t)(n * 2048 + gp)) * 512;
  int l = threadIdx.x; // 64
  f32x4 a = ((const f32x4*)s)[l*2];
  f32x4 c = ((const f32x4*)s)[l*2+1];
  u16x4 o1, o2;
  o1[0]=f2b(a[0]); o1[1]=f2b(a[1]); o1[2]=f2b(a[2]); o1[3]=f2b(a[3]);
  o2[0]=f2b(c[0]); o2[1]=f2b(c[1]); o2[2]=f2b(c[2]); o2[3]=f2b(c[3]);
  ((u16x4*)d)[l*2] = o1; ((u16x4*)d)[l*2+1] = o2;
  if (l == 0 && bias_out) bias_out[n*2048 + gp] = b1[bid] + b2[bid];
}

// ---- plain fp32 -> bf16 cast, 8 elems/thread ----
__global__ void k_cast(const float* __restrict__ src, unsigned short* __restrict__ dst)
{
  int i = blockIdx.x * 256 + threadIdx.x;
  f32x4 a = ((const f32x4*)src)[i*2];
  f32x4 c = ((const f32x4*)src)[i*2+1];
  u16x4 o1, o2;
  o1[0]=f2b(a[0]); o1[1]=f2b(a[1]); o1[2]=f2b(a[2]); o1[3]=f2b(a[3]);
  o2[0]=f2b(c[0]); o2[1]=f2b(c[1]); o2[2]=f2b(c[2]); o2[3]=f2b(c[3]);
  ((u16x4*)dst)[i*2] = o1; ((u16x4*)dst)[i*2+1] = o2;
}

// ---- transpose W_np [n][d][r] -> WnpT [n][r][d] (bf16 out) ----
__global__ void k_transpose_np(const float* __restrict__ src, unsigned short* __restrict__ dst)
{
  __shared__ float tile[64][65];
  int bid = blockIdx.x;                 // n*64 + dt*8 + rt
  int n = bid >> 6, dt = (bid >> 3) & 7, rt = bid & 7;
  int tid = threadIdx.x;
  int row = tid >> 2, c4 = (tid & 3) * 16;
  const float* s = src + ((size_t)n*512 + dt*64 + row)*512 + rt*64 + c4;
#pragma unroll
  for (int i = 0; i < 16; i += 4){
    f32x4 v = *(const f32x4*)(s + i);
    tile[row][c4+i] = v[0]; tile[row][c4+i+1] = v[1];
    tile[row][c4+i+2] = v[2]; tile[row][c4+i+3] = v[3];
  }
  __syncthreads();
  unsigned short* d = dst + ((size_t)n*512 + rt*64 + row)*512 + dt*64 + c4;
#pragma unroll
  for (int i = 0; i < 16; i += 4){
    u16x4 o;
    o[0]=f2b(tile[c4+i][row]);   o[1]=f2b(tile[c4+i+1][row]);
    o[2]=f2b(tile[c4+i+2][row]); o[3]=f2b(tile[c4+i+3][row]);
    *(u16x4*)(d + i) = o;
  }
}

// ---- transpose op_w [d][e] -> op_wT [e][d] fp32 ----
__global__ void k_transpose_op(const float* __restrict__ src, float* __restrict__ dst)
{
  __shared__ float tile[64][65];
  int bid = blockIdx.x; int dt = bid >> 3, et = bid & 7;
  int tid = threadIdx.x;
  int row = tid >> 2, c4 = (tid & 3) * 16;
  const float* s = src + ((size_t)(dt*64 + row))*512 + et*64 + c4;
#pragma unroll
  for (int i = 0; i < 16; i += 4){
    f32x4 v = *(const f32x4*)(s + i);
    tile[row][c4+i] = v[0]; tile[row][c4+i+1] = v[1];
    tile[row][c4+i+2] = v[2]; tile[row][c4+i+3] = v[3];
  }
  __syncthreads();
  float* d = dst + ((size_t)(et*64 + row))*512 + dt*64 + c4;
#pragma unroll
  for (int i = 0; i < 16; i++) d[i] = tile[c4+i][row];
}

// ---- embedding gather: xs[t*8+b][d] fp32 + bf16 copy ----
__global__ void k_embed(const int* __restrict__ x, const float* __restrict__ emb,
                        float* __restrict__ xs, unsigned short* __restrict__ xs_bf)
{
  int row = blockIdx.x;       // t*8+b
  int t = row >> 3, b = row & 7;
  int tok = x[b*S_ + t];
  const f32x4* e = (const f32x4*)(emb + (size_t)tok*512);
  int l = threadIdx.x; // 64
  f32x4 v0 = e[l*2], v1 = e[l*2+1];
  f32x4* xo = (f32x4*)(xs + (size_t)row*512);
  xo[l*2] = v0; xo[l*2+1] = v1;
  u16x4 o0, o1;
  o0[0]=f2b(v0[0]); o0[1]=f2b(v0[1]); o0[2]=f2b(v0[2]); o0[3]=f2b(v0[3]);
  o1[0]=f2b(v1[0]); o1[1]=f2b(v1[1]); o1[2]=f2b(v1[2]); o1[3]=f2b(v1[3]);
  u16x4* xb = (u16x4*)(xs_bf + (size_t)row*512);
  xb[l*2] = o0; xb[l*2+1] = o1;
}

// ---- init c_state f32, h buffer0 bf16, zero barrier flags ----
__global__ void k_init(const float* __restrict__ h0, const float* __restrict__ c0,
                       float* __restrict__ c_state, unsigned short* __restrict__ h_buf0,
                       unsigned int* __restrict__ flags)
{
  int i = blockIdx.x * 256 + threadIdx.x;   // grid 256 -> 65536 = [16][8][512]
  c_state[i] = c0[i];
  h_buf0[i] = f2b(h0[i]);
  if (blockIdx.x == 0) flags[threadIdx.x] = 0;
}

// ---- generic 128x128-tile bf16 MFMA GEMM ----
template<int MODE>
__global__ __launch_bounds__(256)
void k_gemm(const unsigned short* __restrict__ A, const unsigned short* __restrict__ Bm,
            const float* __restrict__ bias, void* __restrict__ Cout,
            int M, int Ncol, int ldc, int nblocks,
            long strideA, long strideB, long strideC, long strideBias)
{
  __shared__ unsigned short lA[128*56];
  __shared__ unsigned short lB[128*56];
  const unsigned short* Ap = A + (size_t)blockIdx.y * strideA;
  const unsigned short* Bp = Bm + (size_t)blockIdx.y * strideB;
  const float* bp = bias ? bias + (size_t)blockIdx.y * strideBias : nullptr;
  int bid = blockIdx.x;
  int mb = bid / nblocks, nb = bid - mb*nblocks;
  int m0 = mb*128, n0 = nb*128;
  int tid = threadIdx.x;
  int wv = tid >> 6, lane = tid & 63;
  int quad = lane >> 4, l16 = lane & 15;
  int wm = wv & 1, wn = wv >> 1;
  f32x4 acc[4][4];
  f32x4 z = {0.f,0.f,0.f,0.f};
#pragma unroll
  for (int i=0;i<4;i++)
#pragma unroll
    for (int j=0;j<4;j++) acc[i][j] = z;

  int lrow = tid >> 2;
  int lkc  = (tid & 3) * 8;
  for (int k0 = 0; k0 < 512; k0 += 32){
    __syncthreads();
#pragma unroll
    for (int h = 0; h < 2; h++){
      int row = lrow + h*64;
      int ar = m0 + row; if (ar >= M) ar = M - 1;
      u32x4 va = *(const u32x4*)(Ap + (size_t)ar*512 + k0 + lkc);
      *(u32x4*)(lA + row*56 + lkc) = va;
      int br = n0 + row; if (br >= Ncol) br = Ncol - 1;
      u32x4 vb = *(const u32x4*)(Bp + (size_t)br*512 + k0 + lkc);
      *(u32x4*)(lB + row*56 + lkc) = vb;
    }
    __syncthreads();
    short8 af[4], bfr[4];
#pragma unroll
    for (int i=0;i<4;i++)
      af[i] = *(const short8*)(lA + (wm*64 + i*16 + l16)*56 + quad*8);
#pragma unroll
    for (int j=0;j<4;j++)
      bfr[j] = *(const short8*)(lB + (wn*64 + j*16 + l16)*56 + quad*8);
#pragma unroll
    for (int i=0;i<4;i++)
#pragma unroll
      for (int j=0;j<4;j++)
        acc[i][j] = __builtin_amdgcn_mfma_f32_16x16x32_bf16(af[i], bfr[j], acc[i][j], 0, 0, 0);
  }
  // epilogue
#pragma unroll
  for (int j = 0; j < 4; j++){
    int col = n0 + wn*64 + j*16 + l16;
    float bv = 0.0f;
    if (bp != nullptr && col < Ncol) bv = bp[col];
#pragma unroll
    for (int i = 0; i < 4; i++){
      int rbase = m0 + wm*64 + i*16 + quad*4;
      f32x4 v = acc[i][j];
      if (MODE == 0){
        int tt = rbase >> 3, b0 = rbase & 7;
        int nn = col >> 11, gp = col & 2047;
        u16x4 pk;
        pk[0]=f2b(v[0]+bv); pk[1]=f2b(v[1]+bv); pk[2]=f2b(v[2]+bv); pk[3]=f2b(v[3]+bv);
        *(u16x4*)((unsigned short*)Cout + (((size_t)tt*16 + nn)*2048 + (size_t)gp)*8 + b0) = pk;
      } else if (MODE == 1){
        float* O = (float*)Cout + (size_t)blockIdx.y * strideC;
#pragma unroll
        for (int r = 0; r < 4; r++){
          int m = rbase + r;
          if (m < M && col < Ncol) O[(size_t)m*ldc + col] = v[r] + bv;
        }
      } else if (MODE == 2){
        float* O = (float*)Cout;
#pragma unroll
        for (int r = 0; r < 4; r++){
          int m = rbase + r;
          int bb = m & 7, tt = m >> 3;
          O[(size_t)bb*SV_ + (size_t)tt*V_ + col] = v[r] + bv;
        }
      } else {
        unsigned short* O = (unsigned short*)Cout + (size_t)blockIdx.y * strideC;
#pragma unroll
        for (int r = 0; r < 4; r++){
          int m = rbase + r;
          if (m < M && col < Ncol) O[(size_t)m*ldc + col] = f2b(v[r] + bv);
        }
      }
    }
  }
}

// ---- persistent LSTM recurrence over one 64-step chunk ----
// 16 INDEPENDENT layers; WG (n, sl) handles gate-cols [sl*128, sl*128+128) of layer n.
// Sync is PER-LAYER (16 WGs, one flag cacheline). All cross-WG data moves via relaxed
// agent-scope atomics (sc1 -> Infinity Cache); NO fences => no buffer_wbl2/inv per step.
__global__ __launch_bounds__(256, 1)
void k_lstm_persist(const unsigned short* __restrict__ W_hhp,
                    const unsigned short* __restrict__ gates_buf,
                    unsigned short* __restrict__ h_all,
                    unsigned short* __restrict__ h_bufs,   // 2 x [16][8][512] bf16
                    float* __restrict__ h_state, float* __restrict__ c_state,
                    unsigned int* __restrict__ flags, int chunk)
{
  __shared__ __align__(16) unsigned char sh[16384];   // h tile [16 rows][1024 B], XOR-swizzled
  __shared__ float gsh[4][2][8][20];
  const int wg = blockIdx.x;
  const int n = wg >> 4, sl = wg & 15;
  const int tid = threadIdx.x;
  const int wv = tid >> 6, lane = tid & 63;
  const int quad = lane >> 4, l16 = lane & 15;
  const int gp0 = sl*128 + wv*32;          // this wave's first gate-col (2 tiles of 16)

  // weight fragments -> registers (128 regs; unified VGPR/AGPR file)
  short8 wfr[2][16];
#pragma unroll
  for (int ct = 0; ct < 2; ct++){
    const unsigned short* wp = W_hhp + ((size_t)(n*2048 + gp0 + ct*16 + l16))*512 + quad*8;
#pragma unroll
    for (int k = 0; k < 16; k++)
      wfr[ct][k] = *(const short8*)(wp + k*32);
  }

  // pointwise lane (lane<32): pb = batch row, handles adjacent r pair rA, rA+1
  const int pb = (lane >> 2) & 7, prl = lane & 3;
  const int rbase = sl*32 + wv*8;
  const int rA = rbase + prl*2;
  float creg[2] = {0.f, 0.f}, hl[2] = {0.f, 0.f};
  if (lane < 32){
    creg[0] = c_state[((size_t)n*8 + pb)*512 + rA];
    creg[1] = c_state[((size_t)n*8 + pb)*512 + rA + 1];
  }

  // zero pad rows 8..15 of the h tile (stay zero forever)
  { u32x4 z = {0,0,0,0};
    *(u32x4*)(sh + 8192 + tid*32) = z;
    *(u32x4*)(sh + 8192 + tid*32 + 16) = z; }

  const int sb = tid >> 5, skc = tid & 31;      // staging: row b, 32B chunk
  const int sswz = (sb & 7) << 4;
  const int aswz = (l16 & 7) << 4;
  const int fidx = (n << 4) | (lane & 15);      // this layer's 16 flags

  // software-pipelined gates (prefetch next step during current)
  u16x4 g0, g1;
  if (quad < 2){
    const unsigned short* gptr = gates_buf + ((size_t)n*2048 + gp0 + l16)*8 + quad*4;
    g0 = *(const u16x4*)gptr;
    g1 = *(const u16x4*)(gptr + 128);
  }

  for (int ls = 0; ls < CHUNK_; ls++){
    const int t = chunk*CHUNK_ + ls;
    // ---- stage h (8 rows x 512 bf16) LLC -> swizzled LDS (coherent loads) ----
    { const unsigned long long* hin = (const unsigned long long*)
        (h_bufs + (size_t)(t & 1)*65536 + (size_t)n*4096 + (size_t)sb*512 + skc*16);
      unsigned long long q0 = __hip_atomic_load(hin+0, __ATOMIC_RELAXED, __HIP_MEMORY_SCOPE_AGENT);
      unsigned long long q1 = __hip_atomic_load(hin+1, __ATOMIC_RELAXED, __HIP_MEMORY_SCOPE_AGENT);
      unsigned long long q2 = __hip_atomic_load(hin+2, __ATOMIC_RELAXED, __HIP_MEMORY_SCOPE_AGENT);
      unsigned long long q3 = __hip_atomic_load(hin+3, __ATOMIC_RELAXED, __HIP_MEMORY_SCOPE_AGENT);
      union { unsigned long long q[2]; u32x4 v; } a0, a1;
      a0.q[0]=q0; a0.q[1]=q1; a1.q[0]=q2; a1.q[1]=q3;
      *(u32x4*)(sh + sb*1024 + ((skc*32) ^ sswz)) = a0.v;
      *(u32x4*)(sh + sb*1024 + ((skc*32 + 16) ^ sswz)) = a1.v;
    }
    __syncthreads();

    // ---- acc init from prefetched gates; prefetch next step's gates ----
    f32x4 acc0, acc1;
    if (quad < 2){
      acc0[0]=b2f(g0[0]); acc0[1]=b2f(g0[1]); acc0[2]=b2f(g0[2]); acc0[3]=b2f(g0[3]);
      acc1[0]=b2f(g1[0]); acc1[1]=b2f(g1[1]); acc1[2]=b2f(g1[2]); acc1[3]=b2f(g1[3]);
    } else {
      f32x4 z = {0.f,0.f,0.f,0.f};
      acc0 = z; acc1 = z;
    }
    if (ls < CHUNK_-1 && quad < 2){
      const unsigned short* gptr = gates_buf + ((size_t)((ls+1)*16 + n)*2048 + gp0 + l16)*8 + quad*4;
      g0 = *(const u16x4*)gptr;
      g1 = *(const u16x4*)(gptr + 128);
    }

    // ---- h @ W_hh (2 tiles / wave) ----
#pragma unroll
    for (int k = 0; k < 16; k++){
      short8 af = *(const short8*)(sh + l16*1024 + ((k*64 + quad*16) ^ aswz));
      acc0 = __builtin_amdgcn_mfma_f32_16x16x32_bf16(af, wfr[0][k], acc0, 0, 0, 0);
      acc1 = __builtin_amdgcn_mfma_f32_16x16x32_bf16(af, wfr[1][k], acc1, 0, 0, 0);
    }

    // ---- regroup gates per (b,r) via LDS, LSTM pointwise ----
    if (quad < 2){
#pragma unroll
      for (int r = 0; r < 4; r++){
        gsh[wv][0][quad*4+r][l16] = acc0[r];
        gsh[wv][1][quad*4+r][l16] = acc1[r];
      }
    }
    __syncthreads();
    if (lane < 32){
      unsigned int hp = 0;
#pragma unroll
      for (int u = 0; u < 2; u++){
        int e = prl*2 + u;                 // 0..7
        int ct = e >> 2, sub = e & 3;
        float gi = gsh[wv][ct][pb][sub*4+0];
        float gf = gsh[wv][ct][pb][sub*4+1];
        float gg = gsh[wv][ct][pb][sub*4+2];
        float go = gsh[wv][ct][pb][sub*4+3];
        float cv = creg[u];
        float si = 1.f/(1.f + expf(-gi));
        float sf = 1.f/(1.f + expf(-gf));
        float so = 1.f/(1.f + expf(-go));
        float cn = sf*cv + si*tanhf(gg);
        float hn = so*tanhf(cn);
        creg[u] = cn; hl[u] = hn;
        hp |= ((unsigned int)f2b(hn)) << (u*16);
      }
      unsigned int* hb = (unsigned int*)(h_bufs + (size_t)((t+1)&1)*65536
                                         + ((size_t)n*8 + pb)*512 + rA);
      __hip_atomic_store(hb, hp, __ATOMIC_RELAXED, __HIP_MEMORY_SCOPE_AGENT);
      *(unsigned int*)(h_all + ((size_t)n*2048 + (size_t)t*8 + pb)*512 + rA) = hp;
    }

    // ---- per-layer barrier: syncthreads drains stores (vmcnt(0) before s_barrier),
    //      then relaxed flag publish + relaxed poll. No cache-maintenance fences. ----
    if (ls != CHUNK_-1){
      __syncthreads();
      if (tid == 0)
        __hip_atomic_store(flags + wg, (unsigned int)(t+1), __ATOMIC_RELAXED, __HIP_MEMORY_SCOPE_AGENT);
      const unsigned int tgt = (unsigned int)(t+1);
      while (1){
        unsigned int f = __hip_atomic_load(flags + fidx, __ATOMIC_RELAXED, __HIP_MEMORY_SCOPE_AGENT);
        if (__all((int)(f >= tgt))) break;
        __builtin_amdgcn_s_sleep(1);
      }
      asm volatile("" ::: "memory");
    }
  }
  // persist recurrent state (c for next chunk; h f32 for final output)
  if (lane < 32){
    c_state[((size_t)n*8 + pb)*512 + rA]     = creg[0];
    c_state[((size_t)n*8 + pb)*512 + rA + 1] = creg[1];
    h_state[((size_t)n*8 + pb)*512 + rA]     = hl[0];
    h_state[((size_t)n*8 + pb)*512 + rA + 1] = hl[1];
  }
}

// ---- batched attention for one 64-step chunk: scores+softmax+att, f32 ----
__global__ __launch_bounds__(256)
void k_att2(const float* __restrict__ kv, const float* __restrict__ q_all,
            float* __restrict__ att_all, int c)
{
  __shared__ float sV[16][528];
  __shared__ float sQ[512];
  __shared__ float sS[8][16];
  __shared__ float sW[8][16];
  int row = blockIdx.x, tid = threadIdx.x;   // row in [0,512)
  int grow = c*512 + row;                    // global t*8+b
  for (int idx = tid; idx < 2048; idx += 256){
    int nn = idx >> 7, e4 = (idx & 127) * 4;
    f32x4 v = *(const f32x4*)(kv + ((size_t)nn*512 + row)*1024 + 512 + e4);
    *(f32x4*)&sV[nn][e4] = v;
  }
  if (tid < 128){
    f32x4 q4 = *(const f32x4*)(q_all + (size_t)grow*512 + tid*4);
    *(f32x4*)&sQ[tid*4] = q4;
  }
  __syncthreads();
  if (tid < 128){
    int h = tid >> 4, nn = tid & 15;
    const f32x4* kp = (const f32x4*)(kv + ((size_t)nn*512 + row)*1024 + h*64);
    const f32x4* qp = (const f32x4*)(sQ + h*64);
    float s = 0.f;
#pragma unroll
    for (int i = 0; i < 16; i++){
      f32x4 k4 = kp[i], q4 = qp[i];
      s += k4[0]*q4[0] + k4[1]*q4[1] + k4[2]*q4[2] + k4[3]*q4[3];
    }
    sS[h][nn] = s * 0.125f;
  }
  __syncthreads();
  if (tid < 8){
    float mx = -1e30f;
#pragma unroll
    for (int nn = 0; nn < 16; nn++) mx = fmaxf(mx, sS[tid][nn]);
    float ex[16]; float sum = 0.f;
#pragma unroll
    for (int nn = 0; nn < 16; nn++){ ex[nn] = expf(sS[tid][nn] - mx); sum += ex[nn]; }
    float inv = 1.f/sum;
#pragma unroll
    for (int nn = 0; nn < 16; nn++) sW[tid][nn] = ex[nn]*inv;
  }
  __syncthreads();
  for (int d = tid; d < 512; d += 256){
    int h = d >> 6;
    float a = 0.f;
#pragma unroll
    for (int nn = 0; nn < 16; nn++) a += sW[h][nn] * sV[nn][d];
    att_all[(size_t)grow*512 + d] = a;
  }
}

// ---- f32 tiled op-projection + bias + residual: y = att @ op_wT + op_b + xs ----
__global__ __launch_bounds__(256)
void k_opproj(const float* __restrict__ att, const float* __restrict__ opT,
              const float* __restrict__ op_b, const float* __restrict__ xs,
              float* __restrict__ y)
{
  __shared__ float sA[64][36];
  __shared__ float sB[32][68];
  int mb = blockIdx.x >> 3, nb = blockIdx.x & 7;   // 32 x 8
  int m0 = mb*64, n0 = nb*64;
  int tid = threadIdx.x;
  int ty = tid >> 4, tx = tid & 15;
  float acc[4][4] = {};
  int ra = tid >> 2, ka = (tid & 3) * 8;
  int rb = tid >> 3, cbq = (tid & 7) * 8;
  for (int k0 = 0; k0 < 512; k0 += 32){
    __syncthreads();
    f32x4 a0 = *(const f32x4*)(att + (size_t)(m0+ra)*512 + k0 + ka);
    f32x4 a1 = *(const f32x4*)(att + (size_t)(m0+ra)*512 + k0 + ka + 4);
    f32x4 b0 = *(const f32x4*)(opT + (size_t)(k0+rb)*512 + n0 + cbq);
    f32x4 b1 = *(const f32x4*)(opT + (size_t)(k0+rb)*512 + n0 + cbq + 4);
    *(f32x4*)&sA[ra][ka] = a0;   *(f32x4*)&sA[ra][ka+4] = a1;
    *(f32x4*)&sB[rb][cbq] = b0;  *(f32x4*)&sB[rb][cbq+4] = b1;
    __syncthreads();
#pragma unroll
    for (int kk = 0; kk < 32; kk++){
      float av[4], bv[4];
#pragma unroll
      for (int i=0;i<4;i++) av[i] = sA[ty*4+i][kk];
#pragma unroll
      for (int j=0;j<4;j++) bv[j] = sB[kk][tx*4+j];
#pragma unroll
      for (int i=0;i<4;i++)
#pragma unroll
        for (int j=0;j<4;j++) acc[i][j] += av[i]*bv[j];
    }
  }
  f32x4 ob = *(const f32x4*)(op_b + n0 + tx*4);
#pragma unroll
  for (int i=0;i<4;i++){
    int m = m0 + ty*4 + i;
    f32x4 xr = *(const f32x4*)(xs + (size_t)m*512 + n0 + tx*4);
    f32x4 o;
#pragma unroll
    for (int j=0;j<4;j++) o[j] = acc[i][j] + ob[j] + xr[j];
    *(f32x4*)(y + (size_t)m*512 + n0 + tx*4) = o;
  }
}

// ---- layernorm rows -> bf16 mixed ----
__global__ void k_ln(const float* __restrict__ y, const float* __restrict__ ln_g,
                     const float* __restrict__ ln_b, unsigned short* __restrict__ mixed)
{
  int row = blockIdx.x, lane = threadIdx.x;  // 64 threads
  const float* yr = y + (size_t)row*512 + lane*8;
  f32x4 v0 = *(const f32x4*)yr;
  f32x4 v1 = *(const f32x4*)(yr + 4);
  float s = v0[0]+v0[1]+v0[2]+v0[3]+v1[0]+v1[1]+v1[2]+v1[3];
#pragma unroll
  for (int off = 32; off; off >>= 1) s += __shfl_xor(s, off);
  float mu = s * (1.f/512.f);
  float d[8];
#pragma unroll
  for (int i=0;i<4;i++){ d[i] = v0[i]-mu; d[4+i] = v1[i]-mu; }
  float p = 0.f;
#pragma unroll
  for (int i=0;i<8;i++) p += d[i]*d[i];
#pragma unroll
  for (int off = 32; off; off >>= 1) p += __shfl_xor(p, off);
  float rstd = rsqrtf(p*(1.f/512.f) + 1e-5f);
  f32x4 g0 = *(const f32x4*)(ln_g + lane*8);
  f32x4 g1 = *(const f32x4*)(ln_g + lane*8 + 4);
  f32x4 b0 = *(const f32x4*)(ln_b + lane*8);
  f32x4 b1 = *(const f32x4*)(ln_b + lane*8 + 4);
  u16x4 o0, o1;
#pragma unroll
  for (int i=0;i<4;i++){
    o0[i] = f2b(d[i]*rstd*g0[i] + b0[i]);
    o1[i] = f2b(d[4+i]*rstd*g1[i] + b1[i]);
  }
  unsigned short* mr = mixed + (size_t)row*512 + lane*8;
  *(u16x4*)mr = o0; *(u16x4*)(mr + 4) = o1;
}

extern "C" void kernel_launch(void* const* d_in, const int* in_sizes, int n_in,
                              void* d_out, int out_size, void* d_ws, size_t ws_size,
                              hipStream_t stream)
{
  const int*   x      = (const int*)  d_in[0];
  const float* h0     = (const float*)d_in[1];
  const float* c0     = (const float*)d_in[2];
  const float* emb    = (const float*)d_in[3];
  const float* W_ih   = (const float*)d_in[4];
  const float* b_ih   = (const float*)d_in[5];
  const float* W_hh   = (const float*)d_in[6];
  const float* b_hh   = (const float*)d_in[7];
  const float* W_np   = (const float*)d_in[8];
  const float* b_np   = (const float*)d_in[9];
  const float* in_w   = (const float*)d_in[10];
  const float* in_b   = (const float*)d_in[11];
  const float* op_w   = (const float*)d_in[12];
  const float* op_b   = (const float*)d_in[13];
  const float* ln_g   = (const float*)d_in[14];
  const float* ln_b   = (const float*)d_in[15];
  const float* head_w = (const float*)d_in[16];
  const float* head_b = (const float*)d_in[17];
  float* out = (float*)d_out;

  char* p = (char*)d_ws;
  unsigned short* gates_buf = (unsigned short*)p;         p += 33554432; // [64][16][2048][8] bf16; later kv_chunk f32
  unsigned short* WnpT      = (unsigned short*)gates_buf;                // alias: pre-loop only
  unsigned short* W_ihp     = (unsigned short*)p;         p += 33554432; // later att_all+y_all f32
  unsigned short* W_hhp     = (unsigned short*)p;         p += 33554432;
  unsigned short* headw_bf  = (unsigned short*)p;         p += 32768000;
  unsigned short* A_kv      = (unsigned short*)p;         p += 16777216;
  unsigned short* h_all     = (unsigned short*)p;         p += 33554432; // [16][2048][512] bf16
  float*          xs        = (float*)p;                  p += 4194304;
  float*          q_all     = (float*)p;                  p += 4194304;
  unsigned short* mixed_bf  = (unsigned short*)p;         p += 2097152;
  unsigned short* xs_bf     = (unsigned short*)p;         p += 2097152;
  unsigned short* Wkv_bf    = (unsigned short*)p;         p += 1048576;
  unsigned short* Wq_bf     = (unsigned short*)p;         p += 524288;
  float*          op_wT     = (float*)p;                  p += 1048576;
  float*          h_state   = (float*)p;                  p += 262144;
  float*          c_state   = (float*)p;                  p += 262144;
  unsigned short* h_bufs    = (unsigned short*)p;         p += 262144;  // 2 x [16][8][512] bf16
  float*          bias_g    = (float*)p;                  p += 131072;
  float*          bias_kvw  = (float*)p;                  p += 65536;
  unsigned short* bnp_bf    = (unsigned short*)p;         p += 16384;
  unsigned int*   flags     = (unsigned int*)p;           p += 1024;

  // ---- precompute ----
  k_permute_cast<<<32768, 64, 0, stream>>>(W_ih, W_ihp, b_ih, b_hh, bias_g);
  k_permute_cast<<<32768, 64, 0, stream>>>(W_hh, W_hhp, nullptr, nullptr, nullptr);
  k_cast<<<8000, 256, 0, stream>>>(head_w, headw_bf);
  k_cast<<<256, 256, 0, stream>>>(in_w + 512*512, Wkv_bf);   // rows 512..1535 (Wk||Wv)
  k_cast<<<128, 256, 0, stream>>>(in_w, Wq_bf);              // rows 0..511
  k_cast<<<4, 256, 0, stream>>>(b_np, bnp_bf);
  k_transpose_np<<<1024, 256, 0, stream>>>(W_np, WnpT);
  k_transpose_op<<<64, 256, 0, stream>>>(op_w, op_wT);
  // A_kv[n][e'][r] = sum_d Wkv[e'][d] * W_np[n][d][r]
  k_gemm<3><<<dim3(32, 16), 256, 0, stream>>>(Wkv_bf, WnpT, nullptr, A_kv,
                                              1024, 512, 512, 4, 0L, 262144L, 524288L, 0L);
  // bias_kv[n][e'] = sum_d b_np[n][d]*Wkv[e'][d] + in_b[512+e']
  k_gemm<1><<<dim3(8, 1), 256, 0, stream>>>(bnp_bf, Wkv_bf, in_b + 512, bias_kvw,
                                            16, 1024, 1024, 8, 0L, 0L, 0L, 0L);
  k_embed<<<2048, 64, 0, stream>>>(x, emb, xs, xs_bf);
  // q_all = xs @ Wq^T + bq
  k_gemm<1><<<dim3(64, 1), 256, 0, stream>>>(xs_bf, Wq_bf, in_b, q_all,
                                             2048, 512, 512, 4, 0L, 0L, 0L, 0L);
  k_init<<<256, 256, 0, stream>>>(h0, c0, c_state, h_bufs, flags);

  // ---- recurrence: 4 chunks of 64 steps, persistent kernel per chunk ----
  for (int c = 0; c < 4; c++){
    k_gemm<0><<<dim3(1024, 1), 256, 0, stream>>>(xs_bf + (size_t)c*262144, W_ihp, bias_g,
                                                 gates_buf, 512, 32768, 0, 256, 0L, 0L, 0L, 0L);
    k_lstm_persist<<<256, 256, 0, stream>>>(W_hhp, gates_buf, h_all, h_bufs,
                                            h_state, c_state, flags, c);
  }

  // ---- batched kv + attention (gates_buf reused as f32 kv chunk [16][512][1024]) ----
  float* kv_chunk = (float*)gates_buf;
  float* att_all  = (float*)W_ihp;            // 2048x512 f32
  float* y_all    = att_all + 2048*512;       // 2048x512 f32
  for (int c = 0; c < 4; c++){
    k_gemm<1><<<dim3(32, 16), 256, 0, stream>>>(h_all + (size_t)c*262144, A_kv, bias_kvw,
                                                kv_chunk, 512, 1024, 1024, 8,
                                                1048576L, 524288L, 524288L, 1024L);
    k_att2<<<512, 256, 0, stream>>>(kv_chunk, q_all, att_all, c);
  }
  k_opproj<<<256, 256, 0, stream>>>(att_all, op_wT, op_b, xs, y_all);
  k_ln<<<2048, 64, 0, stream>>>(y_all, ln_g, ln_b, mixed_bf);

  // ---- head GEMM: logits[b][t][v] ----
  k_gemm<2><<<dim3(4000, 1), 256, 0, stream>>>(mixed_bf, headw_bf, head_b, out,
                                               2048, 32000, 0, 250, 0L, 0L, 0L, 0L);
  // ---- hf, cf ----
  hipMemcpyAsync(out + (size_t)B_*SV_,         h_state, 65536*sizeof(float),
                 hipMemcpyDeviceToDevice, stream);
  hipMemcpyAsync(out + (size_t)B_*SV_ + 65536, c_state, 65536*sizeof(float),
                 hipMemcpyDeviceToDevice, stream);
}